// Round 17
// baseline (288.236 us; speedup 1.0000x reference)
//
#include <hip/hip_runtime.h>

typedef unsigned short u16;
typedef unsigned int u32;
typedef __bf16 bf16x8 __attribute__((ext_vector_type(8)));
typedef float f32x4 __attribute__((ext_vector_type(4)));

#define HID 256
#define TEMP_INV 2.0f

__device__ __forceinline__ u16 f2b(float f) {
  union { float f; u32 u; } v; v.f = f;
  u32 u = v.u;
  u += 0x7FFFu + ((u >> 16) & 1u);
  return (u16)(u >> 16);
}
__device__ __forceinline__ float u2f(u32 u) { union { u32 u; float f; } v; v.u = u; return v.f; }

typedef __attribute__((address_space(1))) const unsigned int ga_u32;
typedef __attribute__((address_space(3))) unsigned int ls_u32;
__device__ __forceinline__ void gload_lds16(const void* g, void* l) {
  __builtin_amdgcn_global_load_lds((ga_u32*)g, (ls_u32*)l, 16, 0, 0);
}

// ---------------- degree count ----------------
__global__ void deg_count_kernel(const int* __restrict__ src, const int* __restrict__ dst,
                                 float* __restrict__ out_deg, float* __restrict__ in_deg, int E) {
  int e = blockIdx.x * blockDim.x + threadIdx.x;
  if (e < E) {
    atomicAdd(&out_deg[src[e]], 1.0f);
    atomicAdd(&in_deg[dst[e]], 1.0f);
  }
}

// ---------------- fused scan (LDS-staged): offs, cursor, norms ----------------
__global__ __launch_bounds__(256) void scan_fused(const float* __restrict__ in_deg,
                                                  const float* __restrict__ out_deg,
                                                  int* __restrict__ offs, int* __restrict__ cursor,
                                                  float* __restrict__ src_norm,
                                                  float* __restrict__ dst_norm, int N) {
  __shared__ float sdeg[8192];
  __shared__ int sums[256];
  int t = threadIdx.x;
  for (int i = t; i < N; i += 256) sdeg[i] = in_deg[i];
  __syncthreads();
  const int chunk = N / 256;
  int base = t * chunk;
  int loc = 0;
  for (int i = 0; i < chunk; ++i) loc += (int)sdeg[base + i];
  sums[t] = loc;
  __syncthreads();
  for (int d = 1; d < 256; d <<= 1) {
    int v = (t >= d) ? sums[t - d] : 0;
    __syncthreads();
    sums[t] += v;
    __syncthreads();
  }
  int run = (t == 0) ? 0 : sums[t - 1];
  for (int i = 0; i < chunk; ++i) {
    int n = base + i;
    offs[n] = run;
    cursor[n] = run;
    run += (int)sdeg[n];
  }
  if (t == 255) offs[N] = run;
  for (int i = t; i < N; i += 256) {
    float id = sdeg[i], od = out_deg[i];
    dst_norm[i] = id > 0.f ? 1.0f / sqrtf(id) : 0.f;
    src_norm[i] = od > 0.f ? 1.0f / sqrtf(od) : 0.f;
  }
}

__global__ void csr_fill(const int* __restrict__ src, const int* __restrict__ dst,
                         int* __restrict__ cur, int* __restrict__ csr_src, int E) {
  int e = blockIdx.x * 256 + threadIdx.x;
  if (e < E) {
    int pos = atomicAdd(&cur[dst[e]], 1);
    csr_src[pos] = src[e];
  }
}

// ---------------- merged packing: feat->bf16, w1T, w2T, wpT ----------------
__global__ void pack_all(const float* __restrict__ feat,
                         const float* __restrict__ W1, const float* __restrict__ Wt1,
                         const float* __restrict__ W2, const float* __restrict__ Wt2,
                         const float* __restrict__ Wp,
                         u16* __restrict__ featb, u16* __restrict__ w1T,
                         u16* __restrict__ w2T, u16* __restrict__ wpT, int N) {
  const int CVT = N * 128 / 256;
  int bid = blockIdx.x, t = threadIdx.x;
  if (bid < CVT) {
    int i = bid * 256 + t;
    float4 v = ((const float4*)feat)[i];
    ((u32*)featb)[2 * i] = (u32)f2b(v.x) | ((u32)f2b(v.y) << 16);
    ((u32*)featb)[2 * i + 1] = (u32)f2b(v.z) | ((u32)f2b(v.w) << 16);
  } else if (bid < CVT + 1024) {
    int idx = (bid - CVT) * 256 + t;
    int n = idx >> 9, k = idx & 511;
    float v = (n < 256) ? W1[(size_t)k * 256 + n] : Wt1[(size_t)k * 256 + (n - 256)];
    w1T[idx] = f2b(v);
  } else if (bid < CVT + 2048) {
    int idx = (bid - CVT - 1024) * 256 + t;
    int n = idx >> 9, k = idx & 511;
    float v = 0.f;
    if (n < 256) { if (k < 256) v = W2[(size_t)k * 256 + n]; }
    else { if (k >= 256) v = Wt2[(size_t)(k - 256) * 256 + (n - 256)]; }
    w2T[idx] = f2b(v);
  } else {
    int idx = (bid - CVT - 2048) * 256 + t;
    int n = idx >> 8, k = idx & 255;
    wpT[idx] = f2b(Wp[(size_t)k * 256 + n]);
  }
}

// ---------------- bf16 MFMA GEMM, gload_lds + swizzle + dbuf: C = A @ BT^T ----------------
// MODE 0: bf16 out (optional per-row scale); MODE 1: f32 out
template <int MODE>
__global__ __launch_bounds__(256, 2) void gemm_bf16(const u16* __restrict__ A,
                                                    const u16* __restrict__ BT,
                                                    void* __restrict__ outp,
                                                    const float* __restrict__ rowscale,
                                                    int M, int Nn, int K) {
  __shared__ u16 As[2][128 * 64];
  __shared__ u16 Bs[2][128 * 64];
  const int t = threadIdx.x;
  const int lane = t & 63, wave = t >> 6;
  const int wm = wave >> 1, wn = wave & 1;
  const size_t m0 = (size_t)blockIdx.x * 128, n0 = (size_t)blockIdx.y * 128;
  const int r16 = lane & 15, kg = lane >> 4;
  const int NKT = K >> 6;

  f32x4 acc[4][4];
#pragma unroll
  for (int i = 0; i < 4; ++i)
#pragma unroll
    for (int j = 0; j < 4; ++j) acc[i][j] = (f32x4){0.f, 0.f, 0.f, 0.f};

#pragma unroll
  for (int i = 0; i < 4; ++i) {
    int chunk = (i * 4 + wave) * 64 + lane;
    int row = chunk >> 3, lc = (chunk & 7) ^ (row & 7);
    gload_lds16(A + (m0 + row) * (size_t)K + lc * 8, &As[0][chunk * 8]);
    gload_lds16(BT + (n0 + row) * (size_t)K + lc * 8, &Bs[0][chunk * 8]);
  }

  for (int kt = 0; kt < NKT; ++kt) {
    asm volatile("s_waitcnt vmcnt(0)" ::: "memory");
    __syncthreads();
    if (kt + 1 < NKT) {
      int b = (kt + 1) & 1;
#pragma unroll
      for (int i = 0; i < 4; ++i) {
        int chunk = (i * 4 + wave) * 64 + lane;
        int row = chunk >> 3, lc = (chunk & 7) ^ (row & 7);
        gload_lds16(A + (m0 + row) * (size_t)K + (kt + 1) * 64 + lc * 8, &As[b][chunk * 8]);
        gload_lds16(BT + (n0 + row) * (size_t)K + (kt + 1) * 64 + lc * 8, &Bs[b][chunk * 8]);
      }
    }
    const u16* Ab = &As[kt & 1][0];
    const u16* Bb = &Bs[kt & 1][0];
#pragma unroll
    for (int k0 = 0; k0 < 2; ++k0) {
      const int swz = ((k0 * 4 + kg) ^ (r16 & 7)) << 3;
      bf16x8 af[4], bfv[4];
#pragma unroll
      for (int mi = 0; mi < 4; ++mi)
        af[mi] = *(const bf16x8*)&Ab[(wm * 64 + mi * 16 + r16) * 64 + swz];
#pragma unroll
      for (int ni = 0; ni < 4; ++ni)
        bfv[ni] = *(const bf16x8*)&Bb[(wn * 64 + ni * 16 + r16) * 64 + swz];
#pragma unroll
      for (int mi = 0; mi < 4; ++mi)
#pragma unroll
        for (int ni = 0; ni < 4; ++ni)
          acc[mi][ni] = __builtin_amdgcn_mfma_f32_16x16x32_bf16(af[mi], bfv[ni], acc[mi][ni], 0, 0, 0);
    }
  }

#pragma unroll
  for (int mi = 0; mi < 4; ++mi)
#pragma unroll
    for (int rr = 0; rr < 4; ++rr) {
      size_t row = m0 + wm * 64 + mi * 16 + kg * 4 + rr;
      float sc = (MODE == 0 && rowscale) ? rowscale[row] : 1.0f;
#pragma unroll
      for (int ni = 0; ni < 4; ++ni) {
        size_t col = n0 + wn * 64 + ni * 16 + r16;
        if (MODE == 0)
          ((u16*)outp)[row * Nn + col] = f2b(acc[mi][ni][rr] * sc);
        else
          ((float*)outp)[row * Nn + col] = acc[mi][ni][rr];
      }
    }
}

// ---------------- negsim: A-in-regs strip, T14 async-staged LDS (round-13 proven, 50 µs) ----------------
__global__ __launch_bounds__(256, 2) void negsim_strip(const u16* __restrict__ zb,
                                                       float* __restrict__ partial,
                                                       int M, int NJB) {
  int bid = blockIdx.x;
  int bi = 0, cum = 0;
  for (;;) {
    int nch = (NJB - bi + 3) >> 2;
    if (bid < cum + nch) break;
    cum += nch;
    ++bi;
  }
  const int jc = bid - cum;
  const int bj0 = bi + jc * 4;
  const int ntiles = min(4, NJB - bj0);

  __shared__ u16 Bs[128][40];
  __shared__ float red[512];
  const int t = threadIdx.x;
  const int lane = t & 63, wave = t >> 6;
  const int wm = wave >> 1, wn = wave & 1;
  const int r16 = lane & 15, kg = lane >> 4;
  const size_t m0 = (size_t)bi * 128;

  const int sm0 = t >> 2, sk0 = t & 3;
  const int sm1 = (t + 256) >> 2, sk1 = (t + 256) & 3;

  bf16x8 af[4][8];
#pragma unroll
  for (int mi = 0; mi < 4; ++mi) {
    const u16* arow = zb + (m0 + wm * 64 + mi * 16 + r16) * (size_t)HID + kg * 8;
#pragma unroll
    for (int k = 0; k < 8; ++k) af[mi][k] = *(const bf16x8*)(arow + k * 32);
  }

  float rs[4][4];
#pragma unroll
  for (int mi = 0; mi < 4; ++mi)
#pragma unroll
    for (int rr = 0; rr < 4; ++rr) rs[mi][rr] = 0.f;

  for (int tt = 0; tt < ntiles; ++tt) {
    const int bj = bj0 + tt;
    const size_t n0 = (size_t)bj * 128;
    f32x4 acc[4][4];
#pragma unroll
    for (int i = 0; i < 4; ++i)
#pragma unroll
      for (int j = 0; j < 4; ++j) acc[i][j] = (f32x4){0.f, 0.f, 0.f, 0.f};

    bf16x8 p0 = *(const bf16x8*)(zb + (n0 + sm0) * (size_t)HID + sk0 * 8);
    bf16x8 p1 = *(const bf16x8*)(zb + (n0 + sm1) * (size_t)HID + sk1 * 8);

#pragma unroll
    for (int kt = 0; kt < 8; ++kt) {
      bf16x8 q0, q1;
      if (kt < 7) {  // T14: issue next-step loads early
        q0 = *(const bf16x8*)(zb + (n0 + sm0) * (size_t)HID + (kt + 1) * 32 + sk0 * 8);
        q1 = *(const bf16x8*)(zb + (n0 + sm1) * (size_t)HID + (kt + 1) * 32 + sk1 * 8);
      }
      __syncthreads();
      *(bf16x8*)&Bs[sm0][sk0 * 8] = p0;
      *(bf16x8*)&Bs[sm1][sk1 * 8] = p1;
      __syncthreads();
      bf16x8 bfv[4];
#pragma unroll
      for (int ni = 0; ni < 4; ++ni)
        bfv[ni] = *(const bf16x8*)&Bs[wn * 64 + ni * 16 + r16][kg * 8];
#pragma unroll
      for (int mi = 0; mi < 4; ++mi)
#pragma unroll
        for (int ni = 0; ni < 4; ++ni)
          acc[mi][ni] = __builtin_amdgcn_mfma_f32_16x16x32_bf16(af[mi][kt], bfv[ni],
                                                                acc[mi][ni], 0, 0, 0);
      p0 = q0;
      p1 = q1;
    }

#pragma unroll
    for (int mi = 0; mi < 4; ++mi)
#pragma unroll
      for (int ni = 0; ni < 4; ++ni)
#pragma unroll
        for (int rr = 0; rr < 4; ++rr)
          acc[mi][ni][rr] = __expf(acc[mi][ni][rr] * TEMP_INV);

#pragma unroll
    for (int mi = 0; mi < 4; ++mi)
#pragma unroll
      for (int rr = 0; rr < 4; ++rr)
        rs[mi][rr] += acc[mi][0][rr] + acc[mi][1][rr] + acc[mi][2][rr] + acc[mi][3][rr];

    if (bj != bi) {
#pragma unroll
      for (int ni = 0; ni < 4; ++ni) {
        float c = 0.f;
#pragma unroll
        for (int mi = 0; mi < 4; ++mi)
#pragma unroll
          for (int rr = 0; rr < 4; ++rr) c += acc[mi][ni][rr];
        c += __shfl_xor(c, 16, 64);
        c += __shfl_xor(c, 32, 64);
        if (kg == 0) red[wm * 256 + wn * 64 + ni * 16 + r16] = c;
      }
      __syncthreads();
      if (t < 128) partial[(size_t)bi * M + n0 + t] = red[t] + red[256 + t];
    }
  }

  __syncthreads();
#pragma unroll
  for (int mi = 0; mi < 4; ++mi)
#pragma unroll
    for (int rr = 0; rr < 4; ++rr) {
      float s = rs[mi][rr];
      s += __shfl_xor(s, 1, 64);
      s += __shfl_xor(s, 2, 64);
      s += __shfl_xor(s, 4, 64);
      s += __shfl_xor(s, 8, 64);
      if (r16 == 0) red[wn * 128 + wm * 64 + mi * 16 + kg * 4 + rr] = s;
    }
  __syncthreads();
  if (t < 128) partial[(size_t)(NJB + jc) * M + m0 + t] = red[t] + red[128 + t];
}

// ---------------- CSR gather-aggregate, 8-deep MLP ----------------
// Wave owns 8 consecutive edges per stride-32 round: 8 independent uint4 row loads in flight.
template <bool LAYER2>
__global__ __launch_bounds__(256) void agg_csr(const u16* __restrict__ xw,
                                               const int* __restrict__ csr_src,
                                               const int* __restrict__ offs,
                                               const float* __restrict__ dst_norm,
                                               const float* __restrict__ bias_v,
                                               const float* __restrict__ bias_u,
                                               u16* __restrict__ out_b512,
                                               u16* __restrict__ zb,
                                               u16* __restrict__ unb,
                                               u16* __restrict__ vb) {
  __shared__ float comb[4][512];
  const int n = blockIdx.x, t = threadIdx.x;
  const int wave = t >> 6, lane = t & 63;
  const int beg = offs[n], end = offs[n + 1];
  float a[8] = {0.f, 0.f, 0.f, 0.f, 0.f, 0.f, 0.f, 0.f};

  auto accum = [&](uint4 p) {
    a[0] += u2f(p.x << 16); a[1] += u2f(p.x & 0xFFFF0000u);
    a[2] += u2f(p.y << 16); a[3] += u2f(p.y & 0xFFFF0000u);
    a[4] += u2f(p.z << 16); a[5] += u2f(p.z & 0xFFFF0000u);
    a[6] += u2f(p.w << 16); a[7] += u2f(p.w & 0xFFFF0000u);
  };

  int i = beg + wave * 8;
  for (; i + 8 <= end; i += 32) {
    uint4 p[8];
#pragma unroll
    for (int k = 0; k < 8; ++k) {
      int s = csr_src[i + k];
      p[k] = *(const uint4*)(xw + (size_t)s * 512 + lane * 8);
    }
#pragma unroll
    for (int k = 0; k < 8; ++k) accum(p[k]);
  }
  // at most one partial block of <8 edges per wave
#pragma unroll
  for (int k = 0; k < 7; ++k) {
    if (i + k < end) {
      int s = csr_src[i + k];
      accum(*(const uint4*)(xw + (size_t)s * 512 + lane * 8));
    }
  }

  *(float4*)&comb[wave][lane * 8] = make_float4(a[0], a[1], a[2], a[3]);
  *(float4*)&comb[wave][lane * 8 + 4] = make_float4(a[4], a[5], a[6], a[7]);
  __syncthreads();
  int c = 2 * t;
  float v0 = comb[0][c] + comb[1][c] + comb[2][c] + comb[3][c];
  float v1 = comb[0][c + 1] + comb[1][c + 1] + comb[2][c + 1] + comb[3][c + 1];
  float dn = dst_norm[n];
  int cb = c & 255;
  const float* bb = (t < 128) ? bias_v : bias_u;
  v0 = dn * v0 + bb[cb];
  v1 = dn * v1 + bb[cb + 1];
  if (!LAYER2) {
    v0 = fmaxf(v0, 0.f);
    v1 = fmaxf(v1, 0.f);
    ((u32*)out_b512)[(size_t)n * 256 + t] = (u32)f2b(v0) | ((u32)f2b(v1) << 16);
  } else {
    if (t < 128)
      ((u32*)vb)[(size_t)n * 128 + t] = (u32)f2b(v0) | ((u32)f2b(v1) << 16);
    __shared__ float nred[4];
    float ss = v0 * v0 + v1 * v1;
#pragma unroll
    for (int m = 1; m < 64; m <<= 1) ss += __shfl_xor(ss, m, 64);
    if (lane == 0) nred[wave] = ss;
    __syncthreads();
    float inv;
    if (t < 128)
      inv = 1.0f / fmaxf(sqrtf(nred[0] + nred[1]), 1e-12f);
    else
      inv = 1.0f / fmaxf(sqrtf(nred[2] + nred[3]), 1e-12f);
    u32 packed = (u32)f2b(v0 * inv) | ((u32)f2b(v1 * inv) << 16);
    if (t < 128)
      ((u32*)zb)[(size_t)n * 128 + t] = packed;
    else
      ((u32*)unb)[(size_t)n * 128 + (t - 128)] = packed;
  }
}

// ---------------- neg_sim = sum over partial slots (coalesced, thread-per-node) ----------------
__global__ void negsim_reduce(const float* __restrict__ partial, float* __restrict__ neg_sim,
                              int N, int nj) {
  int n = blockIdx.x * 256 + threadIdx.x;
  if (n < N) {
    float s = 0.f;
    for (int j = 0; j < nj; ++j) s += partial[(size_t)j * N + n];
    neg_sim[n] = s;
  }
}

// ---------------- CSR edge scoring, 2-deep per half-wave, inline q-normalize ----------------
__global__ __launch_bounds__(256) void edge_csr(const u16* __restrict__ un,
                                                const float* __restrict__ q_pre,
                                                const float* __restrict__ bp,
                                                const int* __restrict__ csr_src,
                                                const int* __restrict__ offs,
                                                const float* __restrict__ neg_sim,
                                                float* __restrict__ score, int N) {
  __shared__ float cpos[8], cneg[8];
  const int n = blockIdx.x, t = threadIdx.x;
  const int hw = t >> 5, lane = t & 31;  // 8 half-waves x 32 lanes
  const int beg = offs[n], end = offs[n + 1];
  const int deg = end - beg;

  float qf[8];
  {
    float4 qa = *(const float4*)(q_pre + (size_t)n * HID + lane * 8);
    float4 qc = *(const float4*)(q_pre + (size_t)n * HID + lane * 8 + 4);
    const float4 ba = *(const float4*)(bp + lane * 8);
    const float4 bc = *(const float4*)(bp + lane * 8 + 4);
    qf[0] = qa.x + ba.x; qf[1] = qa.y + ba.y; qf[2] = qa.z + ba.z; qf[3] = qa.w + ba.w;
    qf[4] = qc.x + bc.x; qf[5] = qc.y + bc.y; qf[6] = qc.z + bc.z; qf[7] = qc.w + bc.w;
    float ss = 0.f;
#pragma unroll
    for (int j = 0; j < 8; ++j) ss += qf[j] * qf[j];
#pragma unroll
    for (int m = 1; m < 32; m <<= 1) ss += __shfl_xor(ss, m, 64);
    float inv = 1.0f / fmaxf(sqrtf(ss), 1e-12f);
#pragma unroll
    for (int j = 0; j < 8; ++j) qf[j] *= inv;
  }

  auto dot_of = [&](uint4 uv) {
    return u2f(uv.x << 16) * qf[0] + u2f(uv.x & 0xFFFF0000u) * qf[1] +
           u2f(uv.y << 16) * qf[2] + u2f(uv.y & 0xFFFF0000u) * qf[3] +
           u2f(uv.z << 16) * qf[4] + u2f(uv.z & 0xFFFF0000u) * qf[5] +
           u2f(uv.w << 16) * qf[6] + u2f(uv.w & 0xFFFF0000u) * qf[7];
  };

  const float ns = neg_sim[n];
  float poss = 0.f, negs = 0.f;
  // half-wave owns pairs of consecutive edges, stride 16: 2 gathers in flight
  int i = beg + hw * 2;
  for (; i + 2 <= end; i += 16) {
    int s0 = csr_src[i], s1 = csr_src[i + 1];
    uint4 uv0 = *(const uint4*)(un + (size_t)s0 * HID + lane * 8);
    uint4 uv1 = *(const uint4*)(un + (size_t)s1 * HID + lane * 8);
    float d0 = dot_of(uv0), d1 = dot_of(uv1);
#pragma unroll
    for (int m = 1; m < 32; m <<= 1) {
      d0 += __shfl_xor(d0, m, 64);
      d1 += __shfl_xor(d1, m, 64);
    }
    float sim0 = d0 * TEMP_INV, sim1 = d1 * TEMP_INV;
    poss += sim0 + sim1;
    negs += __logf(ns + __expf(sim0)) + __logf(ns + __expf(sim1));
  }
  if (i < end) {  // at most one trailing edge for this half-wave
    int s0 = csr_src[i];
    uint4 uv0 = *(const uint4*)(un + (size_t)s0 * HID + lane * 8);
    float d0 = dot_of(uv0);
#pragma unroll
    for (int m = 1; m < 32; m <<= 1) d0 += __shfl_xor(d0, m, 64);
    float sim0 = d0 * TEMP_INV;
    poss += sim0;
    negs += __logf(ns + __expf(sim0));
  }
  if (lane == 0) { cpos[hw] = poss; cneg[hw] = negs; }
  __syncthreads();
  if (t == 0) {
    float p = 0.f, g = 0.f;
#pragma unroll
    for (int i2 = 0; i2 < 8; ++i2) { p += cpos[i2]; g += cneg[i2]; }
    score[n] = deg > 0 ? (g - p) / (float)deg : 0.f;
  }
}

// ---------------- final mean ----------------
__global__ __launch_bounds__(256) void finalize2(const float* __restrict__ score,
                                                 float* __restrict__ out, int N) {
  float acc = 0.f;
  for (int n = threadIdx.x; n < N; n += 256) acc += score[n];
#pragma unroll
  for (int m = 1; m < 64; m <<= 1) acc += __shfl_xor(acc, m, 64);
  __shared__ float red[4];
  if ((threadIdx.x & 63) == 0) red[threadIdx.x >> 6] = acc;
  __syncthreads();
  if (threadIdx.x == 0) out[0] = (red[0] + red[1] + red[2] + red[3]) / (float)N;
}

extern "C" void kernel_launch(void* const* d_in, const int* in_sizes, int n_in,
                              void* d_out, int out_size, void* d_ws, size_t ws_size,
                              hipStream_t stream) {
  const float* feat = (const float*)d_in[0];
  const int* src = (const int*)d_in[1];
  const int* dst = (const int*)d_in[2];
  const float* W1 = (const float*)d_in[3];
  const float* b1 = (const float*)d_in[4];
  const float* W2 = (const float*)d_in[5];
  const float* b2 = (const float*)d_in[6];
  const float* Wt1 = (const float*)d_in[7];
  const float* bt1 = (const float*)d_in[8];
  const float* Wt2 = (const float*)d_in[9];
  const float* bt2 = (const float*)d_in[10];
  const float* Wp = (const float*)d_in[11];
  const float* bp = (const float*)d_in[12];

  const int N = in_sizes[0] / 512;  // 8192
  const int E = in_sizes[1];        // 262144
  const int NJB = N / 128;          // 64
  const int NSLOT = NJB + 16;       // 80: col slots + row-strip slots (strips of 4)

  int nstrip = 0;
  for (int bi = 0; bi < NJB; ++bi) nstrip += (NJB - bi + 3) >> 2;

  char* w = (char*)d_ws;
  size_t off = 0;
  auto alloc = [&](size_t bytes) -> void* {
    void* p = w + off;
    off = (off + bytes + 255) & ~(size_t)255;
    return p;
  };

  float* out_deg = (float*)alloc((size_t)N * 4);
  float* in_deg = (float*)alloc((size_t)N * 4);
  float* src_nrm = (float*)alloc((size_t)N * 4);
  float* dst_nrm = (float*)alloc((size_t)N * 4);
  float* neg_sim = (float*)alloc((size_t)N * 4);
  float* score = (float*)alloc((size_t)N * 4);
  int* offs = (int*)alloc((size_t)(N + 1) * 4);
  int* cursor = (int*)alloc((size_t)N * 4);
  int* csr_src = (int*)alloc((size_t)E * 4);
  u16* w1T = (u16*)alloc(512 * 512 * 2);
  u16* w2T = (u16*)alloc(512 * 512 * 2);
  u16* wpT = (u16*)alloc(256 * 256 * 2);
  u16* featb = (u16*)alloc((size_t)N * 512 * 2);  // reused later: q_pre (f32 N*256)
  u16* XWb = (u16*)alloc((size_t)N * 512 * 2);    // layer GEMM outputs (gather source)
  u16* hb = (u16*)alloc((size_t)N * 512 * 2);     // layer1 out; later vb in first half
  u16* znorm = (u16*)alloc((size_t)N * 512 * 2);  // zb | unb (normalized bf16)
  float* partial = (float*)alloc((size_t)NSLOT * N * 4);

  float* q_pre = (float*)featb;
  u16* zb = znorm;
  u16* unb = znorm + (size_t)N * 256;
  u16* vb = hb;

  dim3 b256(256);

  // degrees, norms, CSR
  hipMemsetAsync(out_deg, 0, 2 * (size_t)N * 4, stream);
  deg_count_kernel<<<(E + 255) / 256, b256, 0, stream>>>(src, dst, out_deg, in_deg, E);
  scan_fused<<<1, b256, 0, stream>>>(in_deg, out_deg, offs, cursor, src_nrm, dst_nrm, N);
  csr_fill<<<(E + 255) / 256, b256, 0, stream>>>(src, dst, cursor, csr_src, E);

  // pack inputs/weights to bf16
  pack_all<<<N * 128 / 256 + 2048 + 256, b256, 0, stream>>>(feat, W1, Wt1, W2, Wt2, Wp,
                                                            featb, w1T, w2T, wpT, N);

  // layer 1 (online+target fused); gemm epilogue pre-scales rows by src_norm
  gemm_bf16<0><<<dim3(N / 128, 4), b256, 0, stream>>>(featb, w1T, XWb, src_nrm, N, 512, 512);
  agg_csr<false><<<N, b256, 0, stream>>>(XWb, csr_src, offs, dst_nrm, b1, bt1,
                                         hb, nullptr, nullptr, nullptr);

  // layer 2: agg epilogue emits vb + l2norm'd zb/unb directly (no f32 round-trip)
  gemm_bf16<0><<<dim3(N / 128, 4), b256, 0, stream>>>(hb, w2T, XWb, src_nrm, N, 512, 512);
  agg_csr<true><<<N, b256, 0, stream>>>(XWb, csr_src, offs, dst_nrm, b2, bt2,
                                        nullptr, zb, unb, vb);

  // projector q (normalization inlined into edge_csr)
  gemm_bf16<1><<<dim3(N / 128, 2), b256, 0, stream>>>(vb, wpT, q_pre, nullptr, N, 256, 256);

  // neg_sim: T14 async-staged strip kernel over upper triangle
  hipMemsetAsync(partial, 0, (size_t)NSLOT * N * 4, stream);
  negsim_strip<<<nstrip, b256, 0, stream>>>(zb, partial, N, NJB);
  negsim_reduce<<<(N + 255) / 256, b256, 0, stream>>>(partial, neg_sim, N, NSLOT);

  // edge scores (2-deep MLP) + final mean
  edge_csr<<<N, b256, 0, stream>>>(unb, q_pre, bp, csr_src, offs, neg_sim, score, N);
  finalize2<<<1, b256, 0, stream>>>(score, (float*)d_out, N);
}

// Round 18
// 277.474 us; speedup vs baseline: 1.0388x; 1.0388x over previous
//
#include <hip/hip_runtime.h>

typedef unsigned short u16;
typedef unsigned int u32;
typedef __bf16 bf16x8 __attribute__((ext_vector_type(8)));
typedef float f32x4 __attribute__((ext_vector_type(4)));

#define HID 256
#define TEMP_INV 2.0f

__device__ __forceinline__ u16 f2b(float f) {
  union { float f; u32 u; } v; v.f = f;
  u32 u = v.u;
  u += 0x7FFFu + ((u >> 16) & 1u);
  return (u16)(u >> 16);
}
__device__ __forceinline__ float u2f(u32 u) { union { u32 u; float f; } v; v.u = u; return v.f; }

typedef __attribute__((address_space(1))) const unsigned int ga_u32;
typedef __attribute__((address_space(3))) unsigned int ls_u32;
__device__ __forceinline__ void gload_lds16(const void* g, void* l) {
  __builtin_amdgcn_global_load_lds((ga_u32*)g, (ls_u32*)l, 16, 0, 0);
}

// ---------------- degree count ----------------
__global__ void deg_count_kernel(const int* __restrict__ src, const int* __restrict__ dst,
                                 float* __restrict__ out_deg, float* __restrict__ in_deg, int E) {
  int e = blockIdx.x * blockDim.x + threadIdx.x;
  if (e < E) {
    atomicAdd(&out_deg[src[e]], 1.0f);
    atomicAdd(&in_deg[dst[e]], 1.0f);
  }
}

// ---------------- fused scan (LDS-staged): offs, cursor, norms ----------------
__global__ __launch_bounds__(256) void scan_fused(const float* __restrict__ in_deg,
                                                  const float* __restrict__ out_deg,
                                                  int* __restrict__ offs, int* __restrict__ cursor,
                                                  float* __restrict__ src_norm,
                                                  float* __restrict__ dst_norm, int N) {
  __shared__ float sdeg[8192];
  __shared__ int sums[256];
  int t = threadIdx.x;
  for (int i = t; i < N; i += 256) sdeg[i] = in_deg[i];
  __syncthreads();
  const int chunk = N / 256;
  int base = t * chunk;
  int loc = 0;
  for (int i = 0; i < chunk; ++i) loc += (int)sdeg[base + i];
  sums[t] = loc;
  __syncthreads();
  for (int d = 1; d < 256; d <<= 1) {
    int v = (t >= d) ? sums[t - d] : 0;
    __syncthreads();
    sums[t] += v;
    __syncthreads();
  }
  int run = (t == 0) ? 0 : sums[t - 1];
  for (int i = 0; i < chunk; ++i) {
    int n = base + i;
    offs[n] = run;
    cursor[n] = run;
    run += (int)sdeg[n];
  }
  if (t == 255) offs[N] = run;
  for (int i = t; i < N; i += 256) {
    float id = sdeg[i], od = out_deg[i];
    dst_norm[i] = id > 0.f ? 1.0f / sqrtf(id) : 0.f;
    src_norm[i] = od > 0.f ? 1.0f / sqrtf(od) : 0.f;
  }
}

__global__ void csr_fill(const int* __restrict__ src, const int* __restrict__ dst,
                         int* __restrict__ cur, int* __restrict__ csr_src, int E) {
  int e = blockIdx.x * 256 + threadIdx.x;
  if (e < E) {
    int pos = atomicAdd(&cur[dst[e]], 1);
    csr_src[pos] = src[e];
  }
}

// ---------------- merged packing: feat->bf16, w1T, w2T, wpT ----------------
__global__ void pack_all(const float* __restrict__ feat,
                         const float* __restrict__ W1, const float* __restrict__ Wt1,
                         const float* __restrict__ W2, const float* __restrict__ Wt2,
                         const float* __restrict__ Wp,
                         u16* __restrict__ featb, u16* __restrict__ w1T,
                         u16* __restrict__ w2T, u16* __restrict__ wpT, int N) {
  const int CVT = N * 128 / 256;
  int bid = blockIdx.x, t = threadIdx.x;
  if (bid < CVT) {
    int i = bid * 256 + t;
    float4 v = ((const float4*)feat)[i];
    ((u32*)featb)[2 * i] = (u32)f2b(v.x) | ((u32)f2b(v.y) << 16);
    ((u32*)featb)[2 * i + 1] = (u32)f2b(v.z) | ((u32)f2b(v.w) << 16);
  } else if (bid < CVT + 1024) {
    int idx = (bid - CVT) * 256 + t;
    int n = idx >> 9, k = idx & 511;
    float v = (n < 256) ? W1[(size_t)k * 256 + n] : Wt1[(size_t)k * 256 + (n - 256)];
    w1T[idx] = f2b(v);
  } else if (bid < CVT + 2048) {
    int idx = (bid - CVT - 1024) * 256 + t;
    int n = idx >> 9, k = idx & 511;
    float v = 0.f;
    if (n < 256) { if (k < 256) v = W2[(size_t)k * 256 + n]; }
    else { if (k >= 256) v = Wt2[(size_t)(k - 256) * 256 + (n - 256)]; }
    w2T[idx] = f2b(v);
  } else {
    int idx = (bid - CVT - 2048) * 256 + t;
    int n = idx >> 8, k = idx & 255;
    wpT[idx] = f2b(Wp[(size_t)k * 256 + n]);
  }
}

// ---------------- bf16 MFMA GEMM, gload_lds + swizzle + dbuf: C = A @ BT^T ----------------
// MODE 0: bf16 out (optional per-row scale); MODE 1: f32 out
template <int MODE>
__global__ __launch_bounds__(256, 2) void gemm_bf16(const u16* __restrict__ A,
                                                    const u16* __restrict__ BT,
                                                    void* __restrict__ outp,
                                                    const float* __restrict__ rowscale,
                                                    int M, int Nn, int K) {
  __shared__ u16 As[2][128 * 64];
  __shared__ u16 Bs[2][128 * 64];
  const int t = threadIdx.x;
  const int lane = t & 63, wave = t >> 6;
  const int wm = wave >> 1, wn = wave & 1;
  const size_t m0 = (size_t)blockIdx.x * 128, n0 = (size_t)blockIdx.y * 128;
  const int r16 = lane & 15, kg = lane >> 4;
  const int NKT = K >> 6;

  f32x4 acc[4][4];
#pragma unroll
  for (int i = 0; i < 4; ++i)
#pragma unroll
    for (int j = 0; j < 4; ++j) acc[i][j] = (f32x4){0.f, 0.f, 0.f, 0.f};

#pragma unroll
  for (int i = 0; i < 4; ++i) {
    int chunk = (i * 4 + wave) * 64 + lane;
    int row = chunk >> 3, lc = (chunk & 7) ^ (row & 7);
    gload_lds16(A + (m0 + row) * (size_t)K + lc * 8, &As[0][chunk * 8]);
    gload_lds16(BT + (n0 + row) * (size_t)K + lc * 8, &Bs[0][chunk * 8]);
  }

  for (int kt = 0; kt < NKT; ++kt) {
    asm volatile("s_waitcnt vmcnt(0)" ::: "memory");
    __syncthreads();
    if (kt + 1 < NKT) {
      int b = (kt + 1) & 1;
#pragma unroll
      for (int i = 0; i < 4; ++i) {
        int chunk = (i * 4 + wave) * 64 + lane;
        int row = chunk >> 3, lc = (chunk & 7) ^ (row & 7);
        gload_lds16(A + (m0 + row) * (size_t)K + (kt + 1) * 64 + lc * 8, &As[b][chunk * 8]);
        gload_lds16(BT + (n0 + row) * (size_t)K + (kt + 1) * 64 + lc * 8, &Bs[b][chunk * 8]);
      }
    }
    const u16* Ab = &As[kt & 1][0];
    const u16* Bb = &Bs[kt & 1][0];
#pragma unroll
    for (int k0 = 0; k0 < 2; ++k0) {
      const int swz = ((k0 * 4 + kg) ^ (r16 & 7)) << 3;
      bf16x8 af[4], bfv[4];
#pragma unroll
      for (int mi = 0; mi < 4; ++mi)
        af[mi] = *(const bf16x8*)&Ab[(wm * 64 + mi * 16 + r16) * 64 + swz];
#pragma unroll
      for (int ni = 0; ni < 4; ++ni)
        bfv[ni] = *(const bf16x8*)&Bb[(wn * 64 + ni * 16 + r16) * 64 + swz];
#pragma unroll
      for (int mi = 0; mi < 4; ++mi)
#pragma unroll
        for (int ni = 0; ni < 4; ++ni)
          acc[mi][ni] = __builtin_amdgcn_mfma_f32_16x16x32_bf16(af[mi], bfv[ni], acc[mi][ni], 0, 0, 0);
    }
  }

#pragma unroll
  for (int mi = 0; mi < 4; ++mi)
#pragma unroll
    for (int rr = 0; rr < 4; ++rr) {
      size_t row = m0 + wm * 64 + mi * 16 + kg * 4 + rr;
      float sc = (MODE == 0 && rowscale) ? rowscale[row] : 1.0f;
#pragma unroll
      for (int ni = 0; ni < 4; ++ni) {
        size_t col = n0 + wn * 64 + ni * 16 + r16;
        if (MODE == 0)
          ((u16*)outp)[row * Nn + col] = f2b(acc[mi][ni][rr] * sc);
        else
          ((float*)outp)[row * Nn + col] = acc[mi][ni][rr];
      }
    }
}

// ---------------- negsim: A-in-regs strip, T14 async-staged LDS (round-13 proven, 50 µs) ----------------
__global__ __launch_bounds__(256, 2) void negsim_strip(const u16* __restrict__ zb,
                                                       float* __restrict__ partial,
                                                       int M, int NJB) {
  int bid = blockIdx.x;
  int bi = 0, cum = 0;
  for (;;) {
    int nch = (NJB - bi + 3) >> 2;
    if (bid < cum + nch) break;
    cum += nch;
    ++bi;
  }
  const int jc = bid - cum;
  const int bj0 = bi + jc * 4;
  const int ntiles = min(4, NJB - bj0);

  __shared__ u16 Bs[128][40];
  __shared__ float red[512];
  const int t = threadIdx.x;
  const int lane = t & 63, wave = t >> 6;
  const int wm = wave >> 1, wn = wave & 1;
  const int r16 = lane & 15, kg = lane >> 4;
  const size_t m0 = (size_t)bi * 128;

  const int sm0 = t >> 2, sk0 = t & 3;
  const int sm1 = (t + 256) >> 2, sk1 = (t + 256) & 3;

  bf16x8 af[4][8];
#pragma unroll
  for (int mi = 0; mi < 4; ++mi) {
    const u16* arow = zb + (m0 + wm * 64 + mi * 16 + r16) * (size_t)HID + kg * 8;
#pragma unroll
    for (int k = 0; k < 8; ++k) af[mi][k] = *(const bf16x8*)(arow + k * 32);
  }

  float rs[4][4];
#pragma unroll
  for (int mi = 0; mi < 4; ++mi)
#pragma unroll
    for (int rr = 0; rr < 4; ++rr) rs[mi][rr] = 0.f;

  for (int tt = 0; tt < ntiles; ++tt) {
    const int bj = bj0 + tt;
    const size_t n0 = (size_t)bj * 128;
    f32x4 acc[4][4];
#pragma unroll
    for (int i = 0; i < 4; ++i)
#pragma unroll
      for (int j = 0; j < 4; ++j) acc[i][j] = (f32x4){0.f, 0.f, 0.f, 0.f};

    bf16x8 p0 = *(const bf16x8*)(zb + (n0 + sm0) * (size_t)HID + sk0 * 8);
    bf16x8 p1 = *(const bf16x8*)(zb + (n0 + sm1) * (size_t)HID + sk1 * 8);

#pragma unroll
    for (int kt = 0; kt < 8; ++kt) {
      bf16x8 q0, q1;
      if (kt < 7) {  // T14: issue next-step loads early
        q0 = *(const bf16x8*)(zb + (n0 + sm0) * (size_t)HID + (kt + 1) * 32 + sk0 * 8);
        q1 = *(const bf16x8*)(zb + (n0 + sm1) * (size_t)HID + (kt + 1) * 32 + sk1 * 8);
      }
      __syncthreads();
      *(bf16x8*)&Bs[sm0][sk0 * 8] = p0;
      *(bf16x8*)&Bs[sm1][sk1 * 8] = p1;
      __syncthreads();
      bf16x8 bfv[4];
#pragma unroll
      for (int ni = 0; ni < 4; ++ni)
        bfv[ni] = *(const bf16x8*)&Bs[wn * 64 + ni * 16 + r16][kg * 8];
#pragma unroll
      for (int mi = 0; mi < 4; ++mi)
#pragma unroll
        for (int ni = 0; ni < 4; ++ni)
          acc[mi][ni] = __builtin_amdgcn_mfma_f32_16x16x32_bf16(af[mi][kt], bfv[ni],
                                                                acc[mi][ni], 0, 0, 0);
      p0 = q0;
      p1 = q1;
    }

#pragma unroll
    for (int mi = 0; mi < 4; ++mi)
#pragma unroll
      for (int ni = 0; ni < 4; ++ni)
#pragma unroll
        for (int rr = 0; rr < 4; ++rr)
          acc[mi][ni][rr] = __expf(acc[mi][ni][rr] * TEMP_INV);

#pragma unroll
    for (int mi = 0; mi < 4; ++mi)
#pragma unroll
      for (int rr = 0; rr < 4; ++rr)
        rs[mi][rr] += acc[mi][0][rr] + acc[mi][1][rr] + acc[mi][2][rr] + acc[mi][3][rr];

    if (bj != bi) {
#pragma unroll
      for (int ni = 0; ni < 4; ++ni) {
        float c = 0.f;
#pragma unroll
        for (int mi = 0; mi < 4; ++mi)
#pragma unroll
          for (int rr = 0; rr < 4; ++rr) c += acc[mi][ni][rr];
        c += __shfl_xor(c, 16, 64);
        c += __shfl_xor(c, 32, 64);
        if (kg == 0) red[wm * 256 + wn * 64 + ni * 16 + r16] = c;
      }
      __syncthreads();
      if (t < 128) partial[(size_t)bi * M + n0 + t] = red[t] + red[256 + t];
    }
  }

  __syncthreads();
#pragma unroll
  for (int mi = 0; mi < 4; ++mi)
#pragma unroll
    for (int rr = 0; rr < 4; ++rr) {
      float s = rs[mi][rr];
      s += __shfl_xor(s, 1, 64);
      s += __shfl_xor(s, 2, 64);
      s += __shfl_xor(s, 4, 64);
      s += __shfl_xor(s, 8, 64);
      if (r16 == 0) red[wn * 128 + wm * 64 + mi * 16 + kg * 4 + rr] = s;
    }
  __syncthreads();
  if (t < 128) partial[(size_t)(NJB + jc) * M + m0 + t] = red[t] + red[128 + t];
}

// ---------------- CSR gather-aggregate, 4-deep MLP (round-16 proven) ----------------
template <bool LAYER2>
__global__ __launch_bounds__(256) void agg_csr(const u16* __restrict__ xw,
                                               const int* __restrict__ csr_src,
                                               const int* __restrict__ offs,
                                               const float* __restrict__ dst_norm,
                                               const float* __restrict__ bias_v,
                                               const float* __restrict__ bias_u,
                                               u16* __restrict__ out_b512,
                                               u16* __restrict__ zb,
                                               u16* __restrict__ unb,
                                               u16* __restrict__ vb) {
  __shared__ float comb[4][512];
  const int n = blockIdx.x, t = threadIdx.x;
  const int wave = t >> 6, lane = t & 63;
  const int beg = offs[n], end = offs[n + 1];
  float a[8] = {0.f, 0.f, 0.f, 0.f, 0.f, 0.f, 0.f, 0.f};

  auto accum = [&](uint4 p) {
    a[0] += u2f(p.x << 16); a[1] += u2f(p.x & 0xFFFF0000u);
    a[2] += u2f(p.y << 16); a[3] += u2f(p.y & 0xFFFF0000u);
    a[4] += u2f(p.z << 16); a[5] += u2f(p.z & 0xFFFF0000u);
    a[6] += u2f(p.w << 16); a[7] += u2f(p.w & 0xFFFF0000u);
  };

  int i = beg + wave * 4;
  for (; i + 4 <= end; i += 16) {
    int s0 = csr_src[i], s1 = csr_src[i + 1], s2 = csr_src[i + 2], s3 = csr_src[i + 3];
    uint4 p0 = *(const uint4*)(xw + (size_t)s0 * 512 + lane * 8);
    uint4 p1 = *(const uint4*)(xw + (size_t)s1 * 512 + lane * 8);
    uint4 p2 = *(const uint4*)(xw + (size_t)s2 * 512 + lane * 8);
    uint4 p3 = *(const uint4*)(xw + (size_t)s3 * 512 + lane * 8);
    accum(p0); accum(p1); accum(p2); accum(p3);
  }
  // at most one partial block of <4 edges per wave
#pragma unroll
  for (int k = 0; k < 3; ++k) {
    if (i + k < end) {
      int s = csr_src[i + k];
      accum(*(const uint4*)(xw + (size_t)s * 512 + lane * 8));
    }
  }

  *(float4*)&comb[wave][lane * 8] = make_float4(a[0], a[1], a[2], a[3]);
  *(float4*)&comb[wave][lane * 8 + 4] = make_float4(a[4], a[5], a[6], a[7]);
  __syncthreads();
  int c = 2 * t;
  float v0 = comb[0][c] + comb[1][c] + comb[2][c] + comb[3][c];
  float v1 = comb[0][c + 1] + comb[1][c + 1] + comb[2][c + 1] + comb[3][c + 1];
  float dn = dst_norm[n];
  int cb = c & 255;
  const float* bb = (t < 128) ? bias_v : bias_u;
  v0 = dn * v0 + bb[cb];
  v1 = dn * v1 + bb[cb + 1];
  if (!LAYER2) {
    v0 = fmaxf(v0, 0.f);
    v1 = fmaxf(v1, 0.f);
    ((u32*)out_b512)[(size_t)n * 256 + t] = (u32)f2b(v0) | ((u32)f2b(v1) << 16);
  } else {
    if (t < 128)
      ((u32*)vb)[(size_t)n * 128 + t] = (u32)f2b(v0) | ((u32)f2b(v1) << 16);
    __shared__ float nred[4];
    float ss = v0 * v0 + v1 * v1;
#pragma unroll
    for (int m = 1; m < 64; m <<= 1) ss += __shfl_xor(ss, m, 64);
    if (lane == 0) nred[wave] = ss;
    __syncthreads();
    float inv;
    if (t < 128)
      inv = 1.0f / fmaxf(sqrtf(nred[0] + nred[1]), 1e-12f);
    else
      inv = 1.0f / fmaxf(sqrtf(nred[2] + nred[3]), 1e-12f);
    u32 packed = (u32)f2b(v0 * inv) | ((u32)f2b(v1 * inv) << 16);
    if (t < 128)
      ((u32*)zb)[(size_t)n * 128 + t] = packed;
    else
      ((u32*)unb)[(size_t)n * 128 + (t - 128)] = packed;
  }
}

// ---------------- neg_sim = sum over partial slots (coalesced, thread-per-node) ----------------
__global__ void negsim_reduce(const float* __restrict__ partial, float* __restrict__ neg_sim,
                              int N, int nj) {
  int n = blockIdx.x * 256 + threadIdx.x;
  if (n < N) {
    float s = 0.f;
    for (int j = 0; j < nj; ++j) s += partial[(size_t)j * N + n];
    neg_sim[n] = s;
  }
}

// ---------------- CSR edge scoring with inline q-normalize (round-10/16 proven) ----------------
__global__ __launch_bounds__(256) void edge_csr(const u16* __restrict__ un,
                                                const float* __restrict__ q_pre,
                                                const float* __restrict__ bp,
                                                const int* __restrict__ csr_src,
                                                const int* __restrict__ offs,
                                                const float* __restrict__ neg_sim,
                                                float* __restrict__ score, int N) {
  __shared__ float cpos[8], cneg[8];
  const int n = blockIdx.x, t = threadIdx.x;
  const int hw = t >> 5, lane = t & 31;  // 8 half-waves x 32 lanes
  const int beg = offs[n], end = offs[n + 1];
  const int deg = end - beg;

  float qf[8];
  {
    float4 qa = *(const float4*)(q_pre + (size_t)n * HID + lane * 8);
    float4 qc = *(const float4*)(q_pre + (size_t)n * HID + lane * 8 + 4);
    const float4 ba = *(const float4*)(bp + lane * 8);
    const float4 bc = *(const float4*)(bp + lane * 8 + 4);
    qf[0] = qa.x + ba.x; qf[1] = qa.y + ba.y; qf[2] = qa.z + ba.z; qf[3] = qa.w + ba.w;
    qf[4] = qc.x + bc.x; qf[5] = qc.y + bc.y; qf[6] = qc.z + bc.z; qf[7] = qc.w + bc.w;
    float ss = 0.f;
#pragma unroll
    for (int j = 0; j < 8; ++j) ss += qf[j] * qf[j];
#pragma unroll
    for (int m = 1; m < 32; m <<= 1) ss += __shfl_xor(ss, m, 64);
    float inv = 1.0f / fmaxf(sqrtf(ss), 1e-12f);
#pragma unroll
    for (int j = 0; j < 8; ++j) qf[j] *= inv;
  }

  const float ns = neg_sim[n];
  float poss = 0.f, negs = 0.f;
  for (int i = beg + hw; i < end; i += 8) {
    int s = csr_src[i];
    uint4 uv = *(const uint4*)(un + (size_t)s * HID + lane * 8);
    float dot = u2f(uv.x << 16) * qf[0] + u2f(uv.x & 0xFFFF0000u) * qf[1] +
                u2f(uv.y << 16) * qf[2] + u2f(uv.y & 0xFFFF0000u) * qf[3] +
                u2f(uv.z << 16) * qf[4] + u2f(uv.z & 0xFFFF0000u) * qf[5] +
                u2f(uv.w << 16) * qf[6] + u2f(uv.w & 0xFFFF0000u) * qf[7];
#pragma unroll
    for (int m = 1; m < 32; m <<= 1) dot += __shfl_xor(dot, m, 64);
    float sim = dot * TEMP_INV;
    poss += sim;
    negs += __logf(ns + __expf(sim));
  }
  if (lane == 0) { cpos[hw] = poss; cneg[hw] = negs; }
  __syncthreads();
  if (t == 0) {
    float p = 0.f, g = 0.f;
#pragma unroll
    for (int i = 0; i < 8; ++i) { p += cpos[i]; g += cneg[i]; }
    score[n] = deg > 0 ? (g - p) / (float)deg : 0.f;
  }
}

// ---------------- final mean ----------------
__global__ __launch_bounds__(256) void finalize2(const float* __restrict__ score,
                                                 float* __restrict__ out, int N) {
  float acc = 0.f;
  for (int n = threadIdx.x; n < N; n += 256) acc += score[n];
#pragma unroll
  for (int m = 1; m < 64; m <<= 1) acc += __shfl_xor(acc, m, 64);
  __shared__ float red[4];
  if ((threadIdx.x & 63) == 0) red[threadIdx.x >> 6] = acc;
  __syncthreads();
  if (threadIdx.x == 0) out[0] = (red[0] + red[1] + red[2] + red[3]) / (float)N;
}

extern "C" void kernel_launch(void* const* d_in, const int* in_sizes, int n_in,
                              void* d_out, int out_size, void* d_ws, size_t ws_size,
                              hipStream_t stream) {
  const float* feat = (const float*)d_in[0];
  const int* src = (const int*)d_in[1];
  const int* dst = (const int*)d_in[2];
  const float* W1 = (const float*)d_in[3];
  const float* b1 = (const float*)d_in[4];
  const float* W2 = (const float*)d_in[5];
  const float* b2 = (const float*)d_in[6];
  const float* Wt1 = (const float*)d_in[7];
  const float* bt1 = (const float*)d_in[8];
  const float* Wt2 = (const float*)d_in[9];
  const float* bt2 = (const float*)d_in[10];
  const float* Wp = (const float*)d_in[11];
  const float* bp = (const float*)d_in[12];

  const int N = in_sizes[0] / 512;  // 8192
  const int E = in_sizes[1];        // 262144
  const int NJB = N / 128;          // 64
  const int NSLOT = NJB + 16;       // 80: col slots + row-strip slots (strips of 4)

  int nstrip = 0;
  for (int bi = 0; bi < NJB; ++bi) nstrip += (NJB - bi + 3) >> 2;

  char* w = (char*)d_ws;
  size_t off = 0;
  auto alloc = [&](size_t bytes) -> void* {
    void* p = w + off;
    off = (off + bytes + 255) & ~(size_t)255;
    return p;
  };

  float* out_deg = (float*)alloc((size_t)N * 4);
  float* in_deg = (float*)alloc((size_t)N * 4);
  float* src_nrm = (float*)alloc((size_t)N * 4);
  float* dst_nrm = (float*)alloc((size_t)N * 4);
  float* neg_sim = (float*)alloc((size_t)N * 4);
  float* score = (float*)alloc((size_t)N * 4);
  int* offs = (int*)alloc((size_t)(N + 1) * 4);
  int* cursor = (int*)alloc((size_t)N * 4);
  int* csr_src = (int*)alloc((size_t)E * 4);
  u16* w1T = (u16*)alloc(512 * 512 * 2);
  u16* w2T = (u16*)alloc(512 * 512 * 2);
  u16* wpT = (u16*)alloc(256 * 256 * 2);
  u16* featb = (u16*)alloc((size_t)N * 512 * 2);  // reused later: q_pre (f32 N*256)
  u16* XWb = (u16*)alloc((size_t)N * 512 * 2);    // layer GEMM outputs (gather source)
  u16* hb = (u16*)alloc((size_t)N * 512 * 2);     // layer1 out; later vb in first half
  u16* znorm = (u16*)alloc((size_t)N * 512 * 2);  // zb | unb (normalized bf16)
  float* partial = (float*)alloc((size_t)NSLOT * N * 4);

  float* q_pre = (float*)featb;
  u16* zb = znorm;
  u16* unb = znorm + (size_t)N * 256;
  u16* vb = hb;

  dim3 b256(256);

  // degrees, norms, CSR
  hipMemsetAsync(out_deg, 0, 2 * (size_t)N * 4, stream);
  deg_count_kernel<<<(E + 255) / 256, b256, 0, stream>>>(src, dst, out_deg, in_deg, E);
  scan_fused<<<1, b256, 0, stream>>>(in_deg, out_deg, offs, cursor, src_nrm, dst_nrm, N);
  csr_fill<<<(E + 255) / 256, b256, 0, stream>>>(src, dst, cursor, csr_src, E);

  // pack inputs/weights to bf16
  pack_all<<<N * 128 / 256 + 2048 + 256, b256, 0, stream>>>(feat, W1, Wt1, W2, Wt2, Wp,
                                                            featb, w1T, w2T, wpT, N);

  // layer 1 (online+target fused); gemm epilogue pre-scales rows by src_norm
  gemm_bf16<0><<<dim3(N / 128, 4), b256, 0, stream>>>(featb, w1T, XWb, src_nrm, N, 512, 512);
  agg_csr<false><<<N, b256, 0, stream>>>(XWb, csr_src, offs, dst_nrm, b1, bt1,
                                         hb, nullptr, nullptr, nullptr);

  // layer 2: agg epilogue emits vb + l2norm'd zb/unb directly (no f32 round-trip)
  gemm_bf16<0><<<dim3(N / 128, 4), b256, 0, stream>>>(hb, w2T, XWb, src_nrm, N, 512, 512);
  agg_csr<true><<<N, b256, 0, stream>>>(XWb, csr_src, offs, dst_nrm, b2, bt2,
                                        nullptr, zb, unb, vb);

  // projector q (normalization inlined into edge_csr)
  gemm_bf16<1><<<dim3(N / 128, 2), b256, 0, stream>>>(vb, wpT, q_pre, nullptr, N, 256, 256);

  // neg_sim: T14 async-staged strip kernel over upper triangle
  hipMemsetAsync(partial, 0, (size_t)NSLOT * N * 4, stream);
  negsim_strip<<<nstrip, b256, 0, stream>>>(zb, partial, N, NJB);
  negsim_reduce<<<(N + 255) / 256, b256, 0, stream>>>(partial, neg_sim, N, NSLOT);

  // edge scores + final mean (round-16 proven tail)
  edge_csr<<<N, b256, 0, stream>>>(unb, q_pre, bp, csr_src, offs, neg_sim, score, N);
  finalize2<<<1, b256, 0, stream>>>(score, (float*)d_out, N);
}